// Round 5
// baseline (352.924 us; speedup 1.0000x reference)
//
#include <hip/hip_runtime.h>

#define BB 128
#define NN 8192
#define SS 100
#define KK 512
#define SPLIT 25                 // sample chunks per batch row
#define SPB (SS / SPLIT)         // samples per block = 4
#define NT 256                   // threads per block (4 waves - fine residency granularity)
#define EPT 32                   // elements per thread
#define VPT 8                    // float4 loads per thread
#define CAND 512                 // candidate list capacity (threshold bin)
#define NBIN 2048
#define BPT (NBIN / NT)          // bins per thread = 8
#define NWAVE (NT / 64)          // 4

// Linear monotone binning of p into [0,2047]; exactness does not depend on
// the range (clamped bins are handled by exact in-bin ranking).
__device__ __forceinline__ int bin_of(float p) {
    const float SC = 2048.0f / 36.0f;
    const float OF = 12.0f * SC;
    int b = (int)fmaf(p, SC, OF);
    b = b < 0 ? 0 : b;
    return b > 2047 ? 2047 : b;
}

__device__ __forceinline__ float fast_ln(float x) {
    return __builtin_amdgcn_logf(x) * 0.69314718056f;   // v_log_f32 * ln2
}

// MODE 0: write packed-u8 partial counts to ws. MODE 1: atomicAdd into out.
template <int MODE>
__global__ __launch_bounds__(NT, 5) void gumbel_topk_kernel(
    const float* __restrict__ logits,
    const float* __restrict__ uniform,
    void* __restrict__ sink) {

    __shared__ __align__(16) int hist[NBIN];
    __shared__ float candKey[CAND];
    __shared__ int   candIdx[CAND];
    __shared__ int   waveTot[NWAVE];
    __shared__ int   bcastSel;
    __shared__ int   bcastKK;
    __shared__ int   candCnt;

    const int tid  = threadIdx.x;
    const int lane = tid & 63;
    const int wv   = tid >> 6;
    const int b     = blockIdx.x / SPLIT;
    const int chunk = blockIdx.x % SPLIT;

    // ---- logits row into registers (reused across samples)
    float lg[EPT];
    const float* lrow = logits + (size_t)b * NN;
#pragma unroll
    for (int j = 0; j < VPT; ++j) {
        const float4 v = *reinterpret_cast<const float4*>(lrow + j * 1024 + tid * 4);
        lg[j * 4 + 0] = v.x; lg[j * 4 + 1] = v.y;
        lg[j * 4 + 2] = v.z; lg[j * 4 + 3] = v.w;
    }

    // packed per-element counters: 4 x u8 per register (max count SPB=4)
    unsigned cnt4[EPT / 4];
#pragma unroll
    for (int i = 0; i < EPT / 4; ++i) cnt4[i] = 0;

    // ---- initial histogram zero: 2048 ints / 256 threads = one int4 x2 each
    *reinterpret_cast<int4*>(&hist[tid * 8])     = make_int4(0, 0, 0, 0);
    *reinterpret_cast<int4*>(&hist[tid * 8 + 4]) = make_int4(0, 0, 0, 0);
    __syncthreads();

    const int s0 = chunk * SPB;

    for (int si = 0; si < SPB; ++si) {
        const float* urow = uniform + ((size_t)b * SS + (s0 + si)) * NN;

        // ---- load u, transform to p = logit + gumbel (single buffer; the
        // load stall at sample start is hidden by co-resident blocks)
        float p[EPT];
#pragma unroll
        for (int j = 0; j < VPT; ++j) {
            const float4 v = *reinterpret_cast<const float4*>(urow + j * 1024 + tid * 4);
            p[j * 4 + 0] = v.x; p[j * 4 + 1] = v.y;
            p[j * 4 + 2] = v.z; p[j * 4 + 3] = v.w;
        }
#pragma unroll
        for (int e = 0; e < EPT; ++e) {
            const float u = p[e] + 1e-20f;
            const float w = -fast_ln(u) + 1e-20f;
            p[e] = lg[e] - fast_ln(w);
        }

        // A: histogram (hist zeroed by previous sample's B1 phase)
#pragma unroll
        for (int e = 0; e < EPT; ++e)
            atomicAdd(&hist[bin_of(p[e])], 1);
        __syncthreads();                                   // s1

        // B1: read own bins, zero them, wave suffix scan
        const int base = tid * BPT;
        int hloc[BPT];
        int sum = 0;
        {
            const int4 h0 = *reinterpret_cast<const int4*>(&hist[base]);
            const int4 h1 = *reinterpret_cast<const int4*>(&hist[base + 4]);
            hloc[0] = h0.x; hloc[1] = h0.y; hloc[2] = h0.z; hloc[3] = h0.w;
            hloc[4] = h1.x; hloc[5] = h1.y; hloc[6] = h1.z; hloc[7] = h1.w;
            const int4 z = make_int4(0, 0, 0, 0);
            *reinterpret_cast<int4*>(&hist[base])     = z;
            *reinterpret_cast<int4*>(&hist[base + 4]) = z;
#pragma unroll
            for (int i = 0; i < BPT; ++i) sum += hloc[i];
        }
        int suf = sum;   // inclusive suffix sum within wave
#pragma unroll
        for (int d = 1; d < 64; d <<= 1) {
            const int o = __shfl_down(suf, d);
            if (lane + d < 64) suf += o;
        }
        if (lane == 0) waveTot[wv] = suf;
        __syncthreads();                                   // s2

        // B2: locate threshold bin, broadcast
        int above = suf - sum;
        for (int w2 = wv + 1; w2 < NWAVE; ++w2) above += waveTot[w2];
        int cum = above;
#pragma unroll
        for (int i = BPT - 1; i >= 0; --i) {
            const int h = hloc[i];
            if (cum < KK && cum + h >= KK) { bcastSel = base + i; bcastKK = KK - cum; }
            cum += h;
        }
        if (tid == 0) candCnt = 0;
        __syncthreads();                                   // s3

        const int selBin = bcastSel;
        const int kk     = bcastKK;

        // C: collect threshold-bin candidates (typically ~10-40 of 8192)
#pragma unroll
        for (int e = 0; e < EPT; ++e) {
            if (bin_of(p[e]) == selBin) {
                const int pos = atomicAdd(&candCnt, 1);
                if (pos < CAND) {
                    candKey[pos] = p[e];
                    candIdx[pos] = (e >> 2) * 1024 + tid * 4 + (e & 3);
                }
            }
        }
        __syncthreads();                                   // s4

        // E: membership; in-bin elements rank themselves inline
        const int c = candCnt < CAND ? candCnt : CAND;
#pragma unroll
        for (int e = 0; e < EPT; ++e) {
            const int bb = bin_of(p[e]);
            if (bb > selBin) {
                cnt4[e >> 2] += 1u << ((e & 3) * 8);
            } else if (bb == selBin) {
                const float kl = p[e];
                const int   il = (e >> 2) * 1024 + tid * 4 + (e & 3);
                int rank = 0;
                for (int j = 0; j < c; ++j) {
                    const float kj = candKey[j];
                    const int   ij = candIdx[j];
                    rank += (kj > kl || (kj == kl && ij < il)) ? 1 : 0;
                }
                if (rank < kk) cnt4[e >> 2] += 1u << ((e & 3) * 8);
            }
        }
        // no barrier: next A touches only hist (quiet since B1); cand arrays
        // are rewritten only after the next s3.
    }

    if (MODE == 0) {
        // coalesced packed-u8 partial counts; dword dn covers gidx [4dn,4dn+3]
        unsigned* wsrow = reinterpret_cast<unsigned*>(sink) + (size_t)blockIdx.x * (NN / 4);
#pragma unroll
        for (int j = 0; j < VPT; ++j) wsrow[j * NT + tid] = cnt4[j];
    } else {
        float* orow = reinterpret_cast<float*>(sink) + (size_t)b * NN;
#pragma unroll
        for (int e = 0; e < EPT; ++e) {
            const unsigned cc = (cnt4[e >> 2] >> ((e & 3) * 8)) & 0xFFu;
            if (cc) {
                const int gidx = (e >> 2) * 1024 + tid * 4 + (e & 3);
                atomicAdd(orow + gidx, (float)cc * 0.01f);
            }
        }
    }
}

// Sum SPLIT packed-u8 partials per dword (max 4*25=100 per byte: no carry),
// scale by 0.01, write float4. One thread per output dword-group.
__global__ __launch_bounds__(256) void reduce_kernel(
    const unsigned* __restrict__ ws, float* __restrict__ out) {
    const int d  = blockIdx.x * 256 + threadIdx.x;   // dword id, 0..262143
    const int b  = d >> 11;
    const int dn = d & 2047;
    unsigned acc = 0;
#pragma unroll
    for (int ch = 0; ch < SPLIT; ++ch)
        acc += ws[((size_t)(b * SPLIT + ch) << 11) + dn];
    float4 o;
    o.x = (float)(acc & 255u) * 0.01f;
    o.y = (float)((acc >> 8) & 255u) * 0.01f;
    o.z = (float)((acc >> 16) & 255u) * 0.01f;
    o.w = (float)(acc >> 24) * 0.01f;
    *reinterpret_cast<float4*>(out + ((size_t)d << 2)) = o;
}

extern "C" void kernel_launch(void* const* d_in, const int* in_sizes, int n_in,
                              void* d_out, int out_size, void* d_ws, size_t ws_size,
                              hipStream_t stream) {
    const float* logits  = (const float*)d_in[0];   // [128, 8192] f32
    const float* uniform = (const float*)d_in[1];   // [128, 100, 8192] f32
    float* out = (float*)d_out;                     // [128, 8192] f32

    const int grid = BB * SPLIT;                    // 3200 blocks
    const size_t need = (size_t)grid * NN;          // 26.2 MB of u8 partials

    if (ws_size >= need) {
        gumbel_topk_kernel<0><<<grid, NT, 0, stream>>>(logits, uniform, d_ws);
        reduce_kernel<<<(BB * NN / 4) / 256, 256, 0, stream>>>(
            (const unsigned*)d_ws, out);
    } else {
        hipMemsetAsync(out, 0, (size_t)out_size * sizeof(float), stream);
        gumbel_topk_kernel<1><<<grid, NT, 0, stream>>>(logits, uniform, d_out);
    }
}